// Round 1
// baseline (698.506 us; speedup 1.0000x reference)
//
#include <hip/hip_runtime.h>

// ---------------------------------------------------------------------------
// GIN forward: 4x [agg(sum) -> Linear+ReLU -> Linear (+ReLU)] -> mean-pool -> head
// N_NODES=50000, N_EDGES=640000, D=128, N_GRAPHS=64, N_CLASSES=32
// ---------------------------------------------------------------------------

// ---------------- CSR build ----------------

__global__ __launch_bounds__(256) void gin_hist(const int* __restrict__ dst,
                                                int nEdges,
                                                int* __restrict__ counts) {
    int i = blockIdx.x * 256 + threadIdx.x;
    if (i < nEdges) atomicAdd(&counts[dst[i]], 1);
}

__global__ __launch_bounds__(256) void gin_scan1(const int* __restrict__ counts,
                                                 int* __restrict__ offsets,
                                                 int* __restrict__ partials, int n) {
    __shared__ int s[256];
    int t = threadIdx.x;
    int i = blockIdx.x * 256 + t;
    int v = (i < n) ? counts[i] : 0;
    s[t] = v;
    __syncthreads();
    for (int off = 1; off < 256; off <<= 1) {
        int u = 0;
        if (t >= off) u = s[t - off];
        __syncthreads();
        s[t] += u;
        __syncthreads();
    }
    if (i < n) offsets[i] = s[t] - v;          // block-local exclusive
    if (t == 255) partials[blockIdx.x] = s[255];
}

__global__ __launch_bounds__(256) void gin_scan2(int* partials, int nb) {
    __shared__ int s[256];
    int t = threadIdx.x;
    int v = (t < nb) ? partials[t] : 0;
    s[t] = v;
    __syncthreads();
    for (int off = 1; off < 256; off <<= 1) {
        int u = 0;
        if (t >= off) u = s[t - off];
        __syncthreads();
        s[t] += u;
        __syncthreads();
    }
    partials[t] = s[t] - v;                    // exclusive scan of block sums
}

__global__ __launch_bounds__(256) void gin_scan3(int* __restrict__ offsets,
                                                 const int* __restrict__ partials,
                                                 int* __restrict__ cursor,
                                                 int n, int nEdges) {
    int i = blockIdx.x * 256 + threadIdx.x;
    if (i < n) {
        int o = offsets[i] + partials[blockIdx.x];
        offsets[i] = o;
        cursor[i]  = o;
    }
    if (i == 0) offsets[n] = nEdges;
}

__global__ __launch_bounds__(256) void gin_scatter(const int* __restrict__ src,
                                                   const int* __restrict__ dst,
                                                   int nEdges,
                                                   int* __restrict__ cursor,
                                                   int* __restrict__ ssrc) {
    int i = blockIdx.x * 256 + threadIdx.x;
    if (i < nEdges) {
        int p = atomicAdd(&cursor[dst[i]], 1);
        ssrc[p] = src[i];
    }
}

// ---------------- aggregation: z[n] = h[n] + sum_{e in CSR(n)} h[src_e] ------
// one wave per node, float2 per lane (128 floats per node row)

__global__ __launch_bounds__(256) void gin_agg(const float* __restrict__ hin,
                                               const int* __restrict__ offs,
                                               const int* __restrict__ ssrc,
                                               float* __restrict__ zout, int nNodes) {
    int wid  = (blockIdx.x * 256 + threadIdx.x) >> 6;
    int lane = threadIdx.x & 63;
    if (wid >= nNodes) return;
    const float2* h2 = (const float2*)hin;
    float2 acc = h2[(size_t)wid * 64 + lane];   // self term (eps = 0)
    int beg = offs[wid], end = offs[wid + 1];
    int e = beg;
    for (; e + 4 <= end; e += 4) {
        int s0 = ssrc[e], s1 = ssrc[e + 1], s2 = ssrc[e + 2], s3 = ssrc[e + 3];
        float2 a0 = h2[(size_t)s0 * 64 + lane];
        float2 a1 = h2[(size_t)s1 * 64 + lane];
        float2 a2 = h2[(size_t)s2 * 64 + lane];
        float2 a3 = h2[(size_t)s3 * 64 + lane];
        acc.x += (a0.x + a1.x) + (a2.x + a3.x);
        acc.y += (a0.y + a1.y) + (a2.y + a3.y);
    }
    for (; e < end; ++e) {
        int s = ssrc[e];
        float2 a = h2[(size_t)s * 64 + lane];
        acc.x += a.x;
        acc.y += a.y;
    }
    ((float2*)zout)[(size_t)wid * 64 + lane] = acc;
}

// ---------------- GEMM: Y = relu?(X @ W + b), X: nRows x 128, W: 128 x 128 ---
// Block tile 64 rows x 128 cols, thread tile 4x8, k staged in chunks of 32.
// In-place X == Y is safe: each block reads only its own 64 rows (fully staged
// across the 4 k-chunks before any store) and writes only those rows.

__global__ __launch_bounds__(256) void gin_gemm(const float* __restrict__ X,
                                                const float* __restrict__ W,
                                                const float* __restrict__ bias,
                                                float* __restrict__ Y,
                                                int nRows, int doRelu) {
    __shared__ float zs[32 * 68];    // [kk][r], stride 68 (pad: stage-write conflicts)
    __shared__ float wsh[32 * 128];  // [kk][c]
    const int tid = threadIdx.x;
    const int tx = tid & 15;         // col group: cols tx*8 .. tx*8+7
    const int ty = tid >> 4;         // row group: rows ty*4 .. ty*4+3
    const int rowbase = blockIdx.x * 64;

    float acc[4][8];
#pragma unroll
    for (int i = 0; i < 4; ++i)
#pragma unroll
        for (int j = 0; j < 8; ++j) acc[i][j] = 0.f;

    for (int kb = 0; kb < 4; ++kb) {
        const int kbase = kb * 32;
        // stage Z chunk (64 rows x 32 k), transposed into zs[kk][r]
#pragma unroll
        for (int e = tid; e < 512; e += 256) {
            int r = e >> 3, k4 = (e & 7) << 2;
            int row = rowbase + r;
            float4 v = make_float4(0.f, 0.f, 0.f, 0.f);
            if (row < nRows) v = *(const float4*)&X[(size_t)row * 128 + kbase + k4];
            zs[(k4 + 0) * 68 + r] = v.x;
            zs[(k4 + 1) * 68 + r] = v.y;
            zs[(k4 + 2) * 68 + r] = v.z;
            zs[(k4 + 3) * 68 + r] = v.w;
        }
        // stage W chunk (32 k x 128 c)
#pragma unroll
        for (int e = tid; e < 1024; e += 256) {
            int kk = e >> 5, c = (e & 31) << 2;
            *(float4*)&wsh[kk * 128 + c] = *(const float4*)&W[(size_t)(kbase + kk) * 128 + c];
        }
        __syncthreads();
#pragma unroll 8
        for (int kk = 0; kk < 32; ++kk) {
            float4 zv = *(const float4*)&zs[kk * 68 + ty * 4];
            float4 w0 = *(const float4*)&wsh[kk * 128 + tx * 8];
            float4 w1 = *(const float4*)&wsh[kk * 128 + tx * 8 + 4];
            float zr[4] = {zv.x, zv.y, zv.z, zv.w};
            float wc[8] = {w0.x, w0.y, w0.z, w0.w, w1.x, w1.y, w1.z, w1.w};
#pragma unroll
            for (int i = 0; i < 4; ++i)
#pragma unroll
                for (int j = 0; j < 8; ++j) acc[i][j] += zr[i] * wc[j];
        }
        __syncthreads();
    }

    float4 b0 = *(const float4*)&bias[tx * 8];
    float4 b1 = *(const float4*)&bias[tx * 8 + 4];
    float bb[8] = {b0.x, b0.y, b0.z, b0.w, b1.x, b1.y, b1.z, b1.w};
#pragma unroll
    for (int i = 0; i < 4; ++i) {
        int row = rowbase + ty * 4 + i;
        if (row < nRows) {
            float o[8];
#pragma unroll
            for (int j = 0; j < 8; ++j) {
                float v = acc[i][j] + bb[j];
                o[j] = doRelu ? fmaxf(v, 0.f) : v;
            }
            *(float4*)&Y[(size_t)row * 128 + tx * 8]     = make_float4(o[0], o[1], o[2], o[3]);
            *(float4*)&Y[(size_t)row * 128 + tx * 8 + 4] = make_float4(o[4], o[5], o[6], o[7]);
        }
    }
}

// ---------------- mean pool (batch is sorted) + classifier head --------------

__device__ __forceinline__ int lb_search(const int* __restrict__ a, int n, int key) {
    int lo = 0, hi = n;
    while (lo < hi) {
        int m = (lo + hi) >> 1;
        if (a[m] < key) lo = m + 1; else hi = m;
    }
    return lo;
}

__global__ __launch_bounds__(256) void gin_pool(const float* __restrict__ h,
                                                const int* __restrict__ batch, int nNodes,
                                                const float* __restrict__ wlin,
                                                const float* __restrict__ blin,
                                                float* __restrict__ out, int nGraphs) {
    __shared__ float red[256];
    __shared__ float sp[128];
    int g = blockIdx.x;
    int t = threadIdx.x;
    int c = t & 127, half = t >> 7;
    int start = lb_search(batch, nNodes, g);
    int end   = lb_search(batch, nNodes, g + 1);
    float acc = 0.f;
    for (int nidx = start + half; nidx < end; nidx += 2)
        acc += h[(size_t)nidx * 128 + c];
    red[t] = acc;
    __syncthreads();
    if (t < 128) {
        float s = red[t] + red[t + 128];
        float cnt = (float)(end - start);
        float p = s / fmaxf(cnt, 1.0f);
        out[(size_t)g * 128 + c] = p;
        sp[c] = p;
    }
    __syncthreads();
    if (t < 32) {
        float s = blin[t];
        for (int k = 0; k < 128; ++k) s += sp[k] * wlin[k * 32 + t];
        out[(size_t)nGraphs * 128 + g * 32 + t] = s;
    }
}

// ---------------------------------------------------------------------------

extern "C" void kernel_launch(void* const* d_in, const int* in_sizes, int n_in,
                              void* d_out, int out_size, void* d_ws, size_t ws_size,
                              hipStream_t stream) {
    const float* x     = (const float*)d_in[0];
    const int*   ei    = (const int*)d_in[1];
    const int*   batch = (const int*)d_in[2];
    const float* w1    = (const float*)d_in[3];
    const float* b1    = (const float*)d_in[4];
    const float* w2    = (const float*)d_in[5];
    const float* b2    = (const float*)d_in[6];
    const float* wlin  = (const float*)d_in[7];
    const float* blin  = (const float*)d_in[8];
    float* out = (float*)d_out;

    const int nNodes  = in_sizes[0] / 128;            // 50000
    const int nEdges  = in_sizes[1] / 2;              // 640000
    const int nLayers = in_sizes[3] / (128 * 128);    // 4
    const int nGraphs = out_size / 160;               // 64 (128 pooled + 32 logits)

    const int* srcArr = ei;
    const int* dstArr = ei + nEdges;

    // workspace layout (ints then two ping-pong float buffers)
    int* counts   = (int*)d_ws;                // nNodes
    int* offsets  = counts + nNodes;           // nNodes + 1
    int* cursor   = offsets + nNodes + 1;      // nNodes
    int* partials = cursor + nNodes;           // 256
    int* ssrc     = partials + 256;            // nEdges
    size_t intWords = (size_t)nNodes * 3 + 1 + 256 + (size_t)nEdges;
    size_t fOff = (intWords + 31) & ~(size_t)31;   // 128B align for float4
    float* bufA = (float*)d_ws + fOff;
    float* bufB = bufA + (size_t)nNodes * 128;

    // zero counts (and partials; offsets/cursor are fully overwritten)
    hipMemsetAsync(d_ws, 0, ((size_t)nNodes * 3 + 1 + 256) * sizeof(int), stream);

    const int nb  = (nNodes + 255) / 256;
    const int eb  = (nEdges + 255) / 256;

    gin_hist<<<eb, 256, 0, stream>>>(dstArr, nEdges, counts);
    gin_scan1<<<nb, 256, 0, stream>>>(counts, offsets, partials, nNodes);
    gin_scan2<<<1, 256, 0, stream>>>(partials, nb);
    gin_scan3<<<nb, 256, 0, stream>>>(offsets, partials, cursor, nNodes, nEdges);
    gin_scatter<<<eb, 256, 0, stream>>>(srcArr, dstArr, nEdges, cursor, ssrc);

    const int gb = (nNodes + 63) / 64;
    const float* hin = x;
    float* bufs[2] = {bufA, bufB};
    for (int L = 0; L < nLayers; ++L) {
        float* zb = bufs[L & 1];
        gin_agg<<<(nNodes + 3) / 4, 256, 0, stream>>>(hin, offsets, ssrc, zb, nNodes);
        gin_gemm<<<gb, 256, 0, stream>>>(zb, w1 + (size_t)L * 16384, b1 + (size_t)L * 128,
                                         zb, nNodes, 1);
        gin_gemm<<<gb, 256, 0, stream>>>(zb, w2 + (size_t)L * 16384, b2 + (size_t)L * 128,
                                         zb, nNodes, (L < nLayers - 1) ? 1 : 0);
        hin = zb;
    }
    gin_pool<<<nGraphs, 256, 0, stream>>>(hin, batch, nNodes, wlin, blin, out, nGraphs);
}

// Round 2
// 642.716 us; speedup vs baseline: 1.0868x; 1.0868x over previous
//
#include <hip/hip_runtime.h>

// ---------------------------------------------------------------------------
// GIN forward: 4x [agg(sum) -> Linear+ReLU -> Linear (+ReLU)] -> mean-pool -> head
// N_NODES=50000, N_EDGES=640000, D=128, N_GRAPHS=64, N_CLASSES=32
// R2: replace 64-block serial gin_pool (115 us, 2.4% occupancy) with
//     parallel chunked partial-sum (atomicAdd per graph-transition) + tiny finalize.
// ---------------------------------------------------------------------------

// ---------------- CSR build ----------------

__global__ __launch_bounds__(256) void gin_hist(const int* __restrict__ dst,
                                                int nEdges,
                                                int* __restrict__ counts) {
    int i = blockIdx.x * 256 + threadIdx.x;
    if (i < nEdges) atomicAdd(&counts[dst[i]], 1);
}

__global__ __launch_bounds__(256) void gin_scan1(const int* __restrict__ counts,
                                                 int* __restrict__ offsets,
                                                 int* __restrict__ partials, int n) {
    __shared__ int s[256];
    int t = threadIdx.x;
    int i = blockIdx.x * 256 + t;
    int v = (i < n) ? counts[i] : 0;
    s[t] = v;
    __syncthreads();
    for (int off = 1; off < 256; off <<= 1) {
        int u = 0;
        if (t >= off) u = s[t - off];
        __syncthreads();
        s[t] += u;
        __syncthreads();
    }
    if (i < n) offsets[i] = s[t] - v;          // block-local exclusive
    if (t == 255) partials[blockIdx.x] = s[255];
}

__global__ __launch_bounds__(256) void gin_scan2(int* partials, int nb) {
    __shared__ int s[256];
    int t = threadIdx.x;
    int v = (t < nb) ? partials[t] : 0;
    s[t] = v;
    __syncthreads();
    for (int off = 1; off < 256; off <<= 1) {
        int u = 0;
        if (t >= off) u = s[t - off];
        __syncthreads();
        s[t] += u;
        __syncthreads();
    }
    partials[t] = s[t] - v;                    // exclusive scan of block sums
}

__global__ __launch_bounds__(256) void gin_scan3(int* __restrict__ offsets,
                                                 const int* __restrict__ partials,
                                                 int* __restrict__ cursor,
                                                 int n, int nEdges) {
    int i = blockIdx.x * 256 + threadIdx.x;
    if (i < n) {
        int o = offsets[i] + partials[blockIdx.x];
        offsets[i] = o;
        cursor[i]  = o;
    }
    if (i == 0) offsets[n] = nEdges;
}

__global__ __launch_bounds__(256) void gin_scatter(const int* __restrict__ src,
                                                   const int* __restrict__ dst,
                                                   int nEdges,
                                                   int* __restrict__ cursor,
                                                   int* __restrict__ ssrc) {
    int i = blockIdx.x * 256 + threadIdx.x;
    if (i < nEdges) {
        int p = atomicAdd(&cursor[dst[i]], 1);
        ssrc[p] = src[i];
    }
}

// ---------------- aggregation: z[n] = h[n] + sum_{e in CSR(n)} h[src_e] ------
// one wave per node, float2 per lane (128 floats per node row)

__global__ __launch_bounds__(256) void gin_agg(const float* __restrict__ hin,
                                               const int* __restrict__ offs,
                                               const int* __restrict__ ssrc,
                                               float* __restrict__ zout, int nNodes) {
    int wid  = (blockIdx.x * 256 + threadIdx.x) >> 6;
    int lane = threadIdx.x & 63;
    if (wid >= nNodes) return;
    const float2* h2 = (const float2*)hin;
    float2 acc = h2[(size_t)wid * 64 + lane];   // self term (eps = 0)
    int beg = offs[wid], end = offs[wid + 1];
    int e = beg;
    for (; e + 4 <= end; e += 4) {
        int s0 = ssrc[e], s1 = ssrc[e + 1], s2 = ssrc[e + 2], s3 = ssrc[e + 3];
        float2 a0 = h2[(size_t)s0 * 64 + lane];
        float2 a1 = h2[(size_t)s1 * 64 + lane];
        float2 a2 = h2[(size_t)s2 * 64 + lane];
        float2 a3 = h2[(size_t)s3 * 64 + lane];
        acc.x += (a0.x + a1.x) + (a2.x + a3.x);
        acc.y += (a0.y + a1.y) + (a2.y + a3.y);
    }
    for (; e < end; ++e) {
        int s = ssrc[e];
        float2 a = h2[(size_t)s * 64 + lane];
        acc.x += a.x;
        acc.y += a.y;
    }
    ((float2*)zout)[(size_t)wid * 64 + lane] = acc;
}

// ---------------- GEMM: Y = relu?(X @ W + b), X: nRows x 128, W: 128 x 128 ---
// Block tile 64 rows x 128 cols, thread tile 4x8, k staged in chunks of 32.
// In-place X == Y is safe: each block reads only its own 64 rows (fully staged
// across the 4 k-chunks before any store) and writes only those rows.

__global__ __launch_bounds__(256) void gin_gemm(const float* __restrict__ X,
                                                const float* __restrict__ W,
                                                const float* __restrict__ bias,
                                                float* __restrict__ Y,
                                                int nRows, int doRelu) {
    __shared__ float zs[32 * 68];    // [kk][r], stride 68 (pad: stage-write conflicts)
    __shared__ float wsh[32 * 128];  // [kk][c]
    const int tid = threadIdx.x;
    const int tx = tid & 15;         // col group: cols tx*8 .. tx*8+7
    const int ty = tid >> 4;         // row group: rows ty*4 .. ty*4+3
    const int rowbase = blockIdx.x * 64;

    float acc[4][8];
#pragma unroll
    for (int i = 0; i < 4; ++i)
#pragma unroll
        for (int j = 0; j < 8; ++j) acc[i][j] = 0.f;

    for (int kb = 0; kb < 4; ++kb) {
        const int kbase = kb * 32;
        // stage Z chunk (64 rows x 32 k), transposed into zs[kk][r]
#pragma unroll
        for (int e = tid; e < 512; e += 256) {
            int r = e >> 3, k4 = (e & 7) << 2;
            int row = rowbase + r;
            float4 v = make_float4(0.f, 0.f, 0.f, 0.f);
            if (row < nRows) v = *(const float4*)&X[(size_t)row * 128 + kbase + k4];
            zs[(k4 + 0) * 68 + r] = v.x;
            zs[(k4 + 1) * 68 + r] = v.y;
            zs[(k4 + 2) * 68 + r] = v.z;
            zs[(k4 + 3) * 68 + r] = v.w;
        }
        // stage W chunk (32 k x 128 c)
#pragma unroll
        for (int e = tid; e < 1024; e += 256) {
            int kk = e >> 5, c = (e & 31) << 2;
            *(float4*)&wsh[kk * 128 + c] = *(const float4*)&W[(size_t)(kbase + kk) * 128 + c];
        }
        __syncthreads();
#pragma unroll 8
        for (int kk = 0; kk < 32; ++kk) {
            float4 zv = *(const float4*)&zs[kk * 68 + ty * 4];
            float4 w0 = *(const float4*)&wsh[kk * 128 + tx * 8];
            float4 w1 = *(const float4*)&wsh[kk * 128 + tx * 8 + 4];
            float zr[4] = {zv.x, zv.y, zv.z, zv.w};
            float wc[8] = {w0.x, w0.y, w0.z, w0.w, w1.x, w1.y, w1.z, w1.w};
#pragma unroll
            for (int i = 0; i < 4; ++i)
#pragma unroll
                for (int j = 0; j < 8; ++j) acc[i][j] += zr[i] * wc[j];
        }
        __syncthreads();
    }

    float4 b0 = *(const float4*)&bias[tx * 8];
    float4 b1 = *(const float4*)&bias[tx * 8 + 4];
    float bb[8] = {b0.x, b0.y, b0.z, b0.w, b1.x, b1.y, b1.z, b1.w};
#pragma unroll
    for (int i = 0; i < 4; ++i) {
        int row = rowbase + ty * 4 + i;
        if (row < nRows) {
            float o[8];
#pragma unroll
            for (int j = 0; j < 8; ++j) {
                float v = acc[i][j] + bb[j];
                o[j] = doRelu ? fmaxf(v, 0.f) : v;
            }
            *(float4*)&Y[(size_t)row * 128 + tx * 8]     = make_float4(o[0], o[1], o[2], o[3]);
            *(float4*)&Y[(size_t)row * 128 + tx * 8 + 4] = make_float4(o[4], o[5], o[6], o[7]);
        }
    }
}

// ---------------- mean pool, phase 1: chunked partial sums -------------------
// batch is sorted: a 256-node chunk spans ~1-2 graphs, so each thread keeps a
// running accumulator for its current graph and flushes one atomicAdd per
// graph transition. 196 blocks x 256 threads, fully coalesced reads.

#define POOL_CHUNK 256

__global__ __launch_bounds__(256) void gin_pool1(const float* __restrict__ h,
                                                 const int* __restrict__ batch, int nNodes,
                                                 float* __restrict__ gsums) {
    int t = threadIdx.x;
    int c = t & 127, half = t >> 7;
    int start = blockIdx.x * POOL_CHUNK;
    int end = start + POOL_CHUNK;
    if (end > nNodes) end = nNodes;
    int n = start + half;
    if (n >= end) return;
    int gcur = batch[n];
    float acc = 0.f;
    for (; n < end; n += 2) {
        int g = batch[n];
        if (g != gcur) {
            atomicAdd(&gsums[gcur * 128 + c], acc);
            acc = 0.f;
            gcur = g;
        }
        acc += h[(size_t)n * 128 + c];
    }
    atomicAdd(&gsums[gcur * 128 + c], acc);
}

// ---------------- mean pool, phase 2: divide by count + classifier head ------

__device__ __forceinline__ int lb_search(const int* __restrict__ a, int n, int key) {
    int lo = 0, hi = n;
    while (lo < hi) {
        int m = (lo + hi) >> 1;
        if (a[m] < key) lo = m + 1; else hi = m;
    }
    return lo;
}

__global__ __launch_bounds__(128) void gin_pool2(const float* __restrict__ gsums,
                                                 const int* __restrict__ batch, int nNodes,
                                                 const float* __restrict__ wlin,
                                                 const float* __restrict__ blin,
                                                 float* __restrict__ out, int nGraphs) {
    __shared__ float sp[128];
    int g = blockIdx.x;
    int t = threadIdx.x;
    int start = lb_search(batch, nNodes, g);
    int end   = lb_search(batch, nNodes, g + 1);
    float cnt = (float)(end - start);
    float p = gsums[(size_t)g * 128 + t] / fmaxf(cnt, 1.0f);
    out[(size_t)g * 128 + t] = p;
    sp[t] = p;
    __syncthreads();
    if (t < 32) {
        float s = blin[t];
        for (int k = 0; k < 128; ++k) s += sp[k] * wlin[k * 32 + t];
        out[(size_t)nGraphs * 128 + g * 32 + t] = s;
    }
}

// ---------------------------------------------------------------------------

extern "C" void kernel_launch(void* const* d_in, const int* in_sizes, int n_in,
                              void* d_out, int out_size, void* d_ws, size_t ws_size,
                              hipStream_t stream) {
    const float* x     = (const float*)d_in[0];
    const int*   ei    = (const int*)d_in[1];
    const int*   batch = (const int*)d_in[2];
    const float* w1    = (const float*)d_in[3];
    const float* b1    = (const float*)d_in[4];
    const float* w2    = (const float*)d_in[5];
    const float* b2    = (const float*)d_in[6];
    const float* wlin  = (const float*)d_in[7];
    const float* blin  = (const float*)d_in[8];
    float* out = (float*)d_out;

    const int nNodes  = in_sizes[0] / 128;            // 50000
    const int nEdges  = in_sizes[1] / 2;              // 640000
    const int nLayers = in_sizes[3] / (128 * 128);    // 4
    const int nGraphs = out_size / 160;               // 64 (128 pooled + 32 logits)

    const int* srcArr = ei;
    const int* dstArr = ei + nEdges;

    // workspace layout (ints/zeroed floats first, then ssrc, then ping-pong bufs)
    int*   counts   = (int*)d_ws;                 // nNodes
    int*   offsets  = counts + nNodes;            // nNodes + 1
    int*   cursor   = offsets + nNodes + 1;       // nNodes
    int*   partials = cursor + nNodes;            // 256
    float* gsums    = (float*)(partials + 256);   // nGraphs * 128
    int*   ssrc     = (int*)(gsums + (size_t)nGraphs * 128);  // nEdges
    size_t zeroWords = (size_t)nNodes * 3 + 1 + 256 + (size_t)nGraphs * 128;
    size_t intWords  = zeroWords + (size_t)nEdges;
    size_t fOff = (intWords + 31) & ~(size_t)31;  // 128B align for float4
    float* bufA = (float*)d_ws + fOff;
    float* bufB = bufA + (size_t)nNodes * 128;

    // zero counts/partials/gsums (offsets/cursor/ssrc are fully overwritten)
    hipMemsetAsync(d_ws, 0, zeroWords * sizeof(int), stream);

    const int nb = (nNodes + 255) / 256;
    const int eb = (nEdges + 255) / 256;

    gin_hist<<<eb, 256, 0, stream>>>(dstArr, nEdges, counts);
    gin_scan1<<<nb, 256, 0, stream>>>(counts, offsets, partials, nNodes);
    gin_scan2<<<1, 256, 0, stream>>>(partials, nb);
    gin_scan3<<<nb, 256, 0, stream>>>(offsets, partials, cursor, nNodes, nEdges);
    gin_scatter<<<eb, 256, 0, stream>>>(srcArr, dstArr, nEdges, cursor, ssrc);

    const int gb = (nNodes + 63) / 64;
    const float* hin = x;
    float* bufs[2] = {bufA, bufB};
    for (int L = 0; L < nLayers; ++L) {
        float* zb = bufs[L & 1];
        gin_agg<<<(nNodes + 3) / 4, 256, 0, stream>>>(hin, offsets, ssrc, zb, nNodes);
        gin_gemm<<<gb, 256, 0, stream>>>(zb, w1 + (size_t)L * 16384, b1 + (size_t)L * 128,
                                         zb, nNodes, 1);
        gin_gemm<<<gb, 256, 0, stream>>>(zb, w2 + (size_t)L * 16384, b2 + (size_t)L * 128,
                                         zb, nNodes, (L < nLayers - 1) ? 1 : 0);
        hin = zb;
    }
    const int pb = (nNodes + POOL_CHUNK - 1) / POOL_CHUNK;
    gin_pool1<<<pb, 256, 0, stream>>>(hin, batch, nNodes, gsums);
    gin_pool2<<<nGraphs, 128, 0, stream>>>(gsums, batch, nNodes, wlin, blin, out, nGraphs);
}

// Round 3
// 525.323 us; speedup vs baseline: 1.3297x; 1.2235x over previous
//
#include <hip/hip_runtime.h>

// ---------------------------------------------------------------------------
// GIN forward: 4x [agg(sum) -> Linear+ReLU -> Linear (+ReLU)] -> mean-pool -> head
// N_NODES=50000, N_EDGES=640000, D=128, N_GRAPHS=64, N_CLASSES=32
// R3: MLPs via split-bf16 MFMA (x = hi + lo; Xh@Wh + Xl@Wh + Xh@Wl, err ~2^-18)
//     + fuse both GEMMs of a layer into one kernel (y1 stays in LDS)
//     + agg epilogue emits the hi/lo split (same write bytes as fp32).
// ---------------------------------------------------------------------------

typedef short short8 __attribute__((ext_vector_type(8)));
typedef float floatx4 __attribute__((ext_vector_type(4)));

__device__ __forceinline__ unsigned short f2bf(float x) {
    unsigned int u = __float_as_uint(x);
    u += 0x7fffu + ((u >> 16) & 1u);          // RNE
    return (unsigned short)(u >> 16);
}
__device__ __forceinline__ float bf2f(unsigned short h) {
    return __uint_as_float(((unsigned int)h) << 16);
}

// ---------------- CSR build ----------------

__global__ __launch_bounds__(256) void gin_hist(const int* __restrict__ dst,
                                                int nEdges,
                                                int* __restrict__ counts) {
    int i = blockIdx.x * 256 + threadIdx.x;
    if (i < nEdges) atomicAdd(&counts[dst[i]], 1);
}

__global__ __launch_bounds__(256) void gin_scan1(const int* __restrict__ counts,
                                                 int* __restrict__ offsets,
                                                 int* __restrict__ partials, int n) {
    __shared__ int s[256];
    int t = threadIdx.x;
    int i = blockIdx.x * 256 + t;
    int v = (i < n) ? counts[i] : 0;
    s[t] = v;
    __syncthreads();
    for (int off = 1; off < 256; off <<= 1) {
        int u = 0;
        if (t >= off) u = s[t - off];
        __syncthreads();
        s[t] += u;
        __syncthreads();
    }
    if (i < n) offsets[i] = s[t] - v;
    if (t == 255) partials[blockIdx.x] = s[255];
}

__global__ __launch_bounds__(256) void gin_scan2(int* partials, int nb) {
    __shared__ int s[256];
    int t = threadIdx.x;
    int v = (t < nb) ? partials[t] : 0;
    s[t] = v;
    __syncthreads();
    for (int off = 1; off < 256; off <<= 1) {
        int u = 0;
        if (t >= off) u = s[t - off];
        __syncthreads();
        s[t] += u;
        __syncthreads();
    }
    partials[t] = s[t] - v;
}

__global__ __launch_bounds__(256) void gin_scan3(int* __restrict__ offsets,
                                                 const int* __restrict__ partials,
                                                 int* __restrict__ cursor,
                                                 int n, int nEdges) {
    int i = blockIdx.x * 256 + threadIdx.x;
    if (i < n) {
        int o = offsets[i] + partials[blockIdx.x];
        offsets[i] = o;
        cursor[i]  = o;
    }
    if (i == 0) offsets[n] = nEdges;
}

__global__ __launch_bounds__(256) void gin_scatter(const int* __restrict__ src,
                                                   const int* __restrict__ dst,
                                                   int nEdges,
                                                   int* __restrict__ cursor,
                                                   int* __restrict__ ssrc) {
    int i = blockIdx.x * 256 + threadIdx.x;
    if (i < nEdges) {
        int p = atomicAdd(&cursor[dst[i]], 1);
        ssrc[p] = src[i];
    }
}

// ---------------- weight split into MFMA B-fragment order --------------------
// Wf[mat][kc(4)][ct(8)][lane(64)][j(8)], value = W[kc*32+(lane>>4)*8+j][ct*16+(lane&15)]
// mat = 2*L for w1, 2*L+1 for w2.

__global__ __launch_bounds__(256) void gin_wsplit(const float* __restrict__ w1,
                                                  const float* __restrict__ w2,
                                                  unsigned short* __restrict__ whf,
                                                  unsigned short* __restrict__ wlf,
                                                  int total) {
    for (int idx = blockIdx.x * 256 + threadIdx.x; idx < total; idx += gridDim.x * 256) {
        int mat  = idx >> 14;
        int rem  = idx & 16383;
        int kc   = rem >> 12;
        int ct   = (rem >> 9) & 7;
        int lane = (rem >> 3) & 63;
        int j    = rem & 7;
        int row = kc * 32 + (lane >> 4) * 8 + j;
        int col = ct * 16 + (lane & 15);
        int L = mat >> 1;
        const float* W = (mat & 1) ? (w2 + (size_t)L * 16384) : (w1 + (size_t)L * 16384);
        float x = W[row * 128 + col];
        unsigned short h = f2bf(x);
        unsigned short l = f2bf(x - bf2f(h));
        whf[idx] = h;
        wlf[idx] = l;
    }
}

// ---------------- aggregation: z[n] = h[n] + sum_{e} h[src_e], split output --
// one wave per node, float2 per lane; epilogue splits fp32 -> (hi, lo) bf16.

__global__ __launch_bounds__(256) void gin_agg(const float* __restrict__ hin,
                                               const int* __restrict__ offs,
                                               const int* __restrict__ ssrc,
                                               unsigned int* __restrict__ zh,
                                               unsigned int* __restrict__ zl, int nNodes) {
    int wid  = (blockIdx.x * 256 + threadIdx.x) >> 6;
    int lane = threadIdx.x & 63;
    if (wid >= nNodes) return;
    const float2* h2 = (const float2*)hin;
    float2 acc = h2[(size_t)wid * 64 + lane];   // self term (eps = 0)
    int beg = offs[wid], end = offs[wid + 1];
    int e = beg;
    for (; e + 4 <= end; e += 4) {
        int s0 = ssrc[e], s1 = ssrc[e + 1], s2 = ssrc[e + 2], s3 = ssrc[e + 3];
        float2 a0 = h2[(size_t)s0 * 64 + lane];
        float2 a1 = h2[(size_t)s1 * 64 + lane];
        float2 a2 = h2[(size_t)s2 * 64 + lane];
        float2 a3 = h2[(size_t)s3 * 64 + lane];
        acc.x += (a0.x + a1.x) + (a2.x + a3.x);
        acc.y += (a0.y + a1.y) + (a2.y + a3.y);
    }
    for (; e < end; ++e) {
        int s = ssrc[e];
        float2 a = h2[(size_t)s * 64 + lane];
        acc.x += a.x;
        acc.y += a.y;
    }
    unsigned short h0 = f2bf(acc.x), h1 = f2bf(acc.y);
    unsigned short l0 = f2bf(acc.x - bf2f(h0)), l1 = f2bf(acc.y - bf2f(h1));
    zh[(size_t)wid * 64 + lane] = (unsigned)h0 | ((unsigned)h1 << 16);
    zl[(size_t)wid * 64 + lane] = (unsigned)l0 | ((unsigned)l1 << 16);
}

// ---------------- fused MLP: h = [relu](relu(z@W1+b1)@W2+b2) ----------------
// Block = 64 rows x 128 cols, 4 waves. Wave w owns cols w*32..w*32+31
// (coltiles 2w, 2w+1) across all 4 rowgroups. 16x16x32 bf16 MFMA, 3-term split.
// y1 lives in LDS as packed (hi<<16|lo) uint, row stride 132 (bank-safe).

__global__ __launch_bounds__(256) void gin_mlp(const unsigned short* __restrict__ zh,
                                               const unsigned short* __restrict__ zl,
                                               const unsigned short* __restrict__ whf,
                                               const unsigned short* __restrict__ wlf,
                                               int matBase,
                                               const float* __restrict__ b1p,
                                               const float* __restrict__ b2p,
                                               float* __restrict__ hout,
                                               int nRows, int doRelu2) {
    __shared__ unsigned int y1s[64 * 132];
    const int tid = threadIdx.x;
    const int w = tid >> 6, lane = tid & 63;
    const int lo4 = lane & 15, hi4 = lane >> 4;
    const int rowbase = blockIdx.x * 64;

    short8 bh[2][4], bl[2][4];
#pragma unroll
    for (int ct = 0; ct < 2; ++ct)
#pragma unroll
        for (int kc = 0; kc < 4; ++kc) {
            size_t o = ((((size_t)matBase * 4 + kc) * 8 + (2 * w + ct)) * 64 + lane) * 8;
            bh[ct][kc] = *(const short8*)(whf + o);
            bl[ct][kc] = *(const short8*)(wlf + o);
        }

    floatx4 acc[4][2];
#pragma unroll
    for (int rg = 0; rg < 4; ++rg)
#pragma unroll
        for (int ct = 0; ct < 2; ++ct) acc[rg][ct] = (floatx4)0.f;

    // ---- phase 1: y1 = relu(z @ W1 + b1)
#pragma unroll
    for (int rg = 0; rg < 4; ++rg) {
        int row = rowbase + rg * 16 + lo4;
        bool ok = row < nRows;
        const unsigned short* pzh = zh + (size_t)row * 128 + hi4 * 8;
        const unsigned short* pzl = zl + (size_t)row * 128 + hi4 * 8;
#pragma unroll
        for (int kc = 0; kc < 4; ++kc) {
            short8 ah = {0,0,0,0,0,0,0,0}, al = {0,0,0,0,0,0,0,0};
            if (ok) {
                ah = *(const short8*)(pzh + kc * 32);
                al = *(const short8*)(pzl + kc * 32);
            }
#pragma unroll
            for (int ct = 0; ct < 2; ++ct) {
                acc[rg][ct] = __builtin_amdgcn_mfma_f32_16x16x32_bf16(ah, bh[ct][kc], acc[rg][ct], 0, 0, 0);
                acc[rg][ct] = __builtin_amdgcn_mfma_f32_16x16x32_bf16(al, bh[ct][kc], acc[rg][ct], 0, 0, 0);
                acc[rg][ct] = __builtin_amdgcn_mfma_f32_16x16x32_bf16(ah, bl[ct][kc], acc[rg][ct], 0, 0, 0);
            }
        }
    }

    // epilogue 1: bias + relu + split -> LDS (packed hi|lo)
    float bb1_0 = b1p[w * 32 + lo4];
    float bb1_1 = b1p[w * 32 + 16 + lo4];
#pragma unroll
    for (int rg = 0; rg < 4; ++rg)
#pragma unroll
        for (int ct = 0; ct < 2; ++ct) {
            float bb = ct ? bb1_1 : bb1_0;
#pragma unroll
            for (int r = 0; r < 4; ++r) {
                float v = fmaxf(acc[rg][ct][r] + bb, 0.f);
                unsigned short h = f2bf(v);
                unsigned short l = f2bf(v - bf2f(h));
                int rl = rg * 16 + hi4 * 4 + r;
                int cl = w * 32 + ct * 16 + lo4;
                y1s[rl * 132 + cl] = ((unsigned)h << 16) | (unsigned)l;
            }
        }
    __syncthreads();

    // ---- phase 2: h = y1 @ W2 + b2
#pragma unroll
    for (int ct = 0; ct < 2; ++ct)
#pragma unroll
        for (int kc = 0; kc < 4; ++kc) {
            size_t o = ((((size_t)(matBase + 1) * 4 + kc) * 8 + (2 * w + ct)) * 64 + lane) * 8;
            bh[ct][kc] = *(const short8*)(whf + o);
            bl[ct][kc] = *(const short8*)(wlf + o);
        }
#pragma unroll
    for (int rg = 0; rg < 4; ++rg)
#pragma unroll
        for (int ct = 0; ct < 2; ++ct) acc[rg][ct] = (floatx4)0.f;

#pragma unroll
    for (int rg = 0; rg < 4; ++rg) {
#pragma unroll
        for (int kc = 0; kc < 4; ++kc) {
            const unsigned int* p = &y1s[(rg * 16 + lo4) * 132 + kc * 32 + hi4 * 8];
            uint4 u0 = *(const uint4*)p;
            uint4 u1 = *(const uint4*)(p + 4);
            short8 ah, al;
            ah[0] = (short)(u0.x >> 16); al[0] = (short)u0.x;
            ah[1] = (short)(u0.y >> 16); al[1] = (short)u0.y;
            ah[2] = (short)(u0.z >> 16); al[2] = (short)u0.z;
            ah[3] = (short)(u0.w >> 16); al[3] = (short)u0.w;
            ah[4] = (short)(u1.x >> 16); al[4] = (short)u1.x;
            ah[5] = (short)(u1.y >> 16); al[5] = (short)u1.y;
            ah[6] = (short)(u1.z >> 16); al[6] = (short)u1.z;
            ah[7] = (short)(u1.w >> 16); al[7] = (short)u1.w;
#pragma unroll
            for (int ct = 0; ct < 2; ++ct) {
                acc[rg][ct] = __builtin_amdgcn_mfma_f32_16x16x32_bf16(ah, bh[ct][kc], acc[rg][ct], 0, 0, 0);
                acc[rg][ct] = __builtin_amdgcn_mfma_f32_16x16x32_bf16(al, bh[ct][kc], acc[rg][ct], 0, 0, 0);
                acc[rg][ct] = __builtin_amdgcn_mfma_f32_16x16x32_bf16(ah, bl[ct][kc], acc[rg][ct], 0, 0, 0);
            }
        }
    }

    float bb2_0 = b2p[w * 32 + lo4];
    float bb2_1 = b2p[w * 32 + 16 + lo4];
#pragma unroll
    for (int rg = 0; rg < 4; ++rg)
#pragma unroll
        for (int ct = 0; ct < 2; ++ct) {
            float bb = ct ? bb2_1 : bb2_0;
#pragma unroll
            for (int r = 0; r < 4; ++r) {
                int row = rowbase + rg * 16 + hi4 * 4 + r;
                if (row < nRows) {
                    float v = acc[rg][ct][r] + bb;
                    if (doRelu2) v = fmaxf(v, 0.f);
                    hout[(size_t)row * 128 + w * 32 + ct * 16 + lo4] = v;
                }
            }
        }
}

// ---------------- mean pool, phase 1: chunked partial sums -------------------

#define POOL_CHUNK 256

__global__ __launch_bounds__(256) void gin_pool1(const float* __restrict__ h,
                                                 const int* __restrict__ batch, int nNodes,
                                                 float* __restrict__ gsums) {
    int t = threadIdx.x;
    int c = t & 127, half = t >> 7;
    int start = blockIdx.x * POOL_CHUNK;
    int end = start + POOL_CHUNK;
    if (end > nNodes) end = nNodes;
    int n = start + half;
    if (n >= end) return;
    int gcur = batch[n];
    float acc = 0.f;
    for (; n < end; n += 2) {
        int g = batch[n];
        if (g != gcur) {
            atomicAdd(&gsums[gcur * 128 + c], acc);
            acc = 0.f;
            gcur = g;
        }
        acc += h[(size_t)n * 128 + c];
    }
    atomicAdd(&gsums[gcur * 128 + c], acc);
}

// ---------------- mean pool, phase 2: divide by count + classifier head ------

__device__ __forceinline__ int lb_search(const int* __restrict__ a, int n, int key) {
    int lo = 0, hi = n;
    while (lo < hi) {
        int m = (lo + hi) >> 1;
        if (a[m] < key) lo = m + 1; else hi = m;
    }
    return lo;
}

__global__ __launch_bounds__(128) void gin_pool2(const float* __restrict__ gsums,
                                                 const int* __restrict__ batch, int nNodes,
                                                 const float* __restrict__ wlin,
                                                 const float* __restrict__ blin,
                                                 float* __restrict__ out, int nGraphs) {
    __shared__ float sp[128];
    int g = blockIdx.x;
    int t = threadIdx.x;
    int start = lb_search(batch, nNodes, g);
    int end   = lb_search(batch, nNodes, g + 1);
    float cnt = (float)(end - start);
    float p = gsums[(size_t)g * 128 + t] / fmaxf(cnt, 1.0f);
    out[(size_t)g * 128 + t] = p;
    sp[t] = p;
    __syncthreads();
    if (t < 32) {
        float s = blin[t];
        for (int k = 0; k < 128; ++k) s += sp[k] * wlin[k * 32 + t];
        out[(size_t)nGraphs * 128 + g * 32 + t] = s;
    }
}

// ---------------------------------------------------------------------------

extern "C" void kernel_launch(void* const* d_in, const int* in_sizes, int n_in,
                              void* d_out, int out_size, void* d_ws, size_t ws_size,
                              hipStream_t stream) {
    const float* x     = (const float*)d_in[0];
    const int*   ei    = (const int*)d_in[1];
    const int*   batch = (const int*)d_in[2];
    const float* w1    = (const float*)d_in[3];
    const float* b1    = (const float*)d_in[4];
    const float* w2    = (const float*)d_in[5];
    const float* b2    = (const float*)d_in[6];
    const float* wlin  = (const float*)d_in[7];
    const float* blin  = (const float*)d_in[8];
    float* out = (float*)d_out;

    const int nNodes  = in_sizes[0] / 128;            // 50000
    const int nEdges  = in_sizes[1] / 2;              // 640000
    const int nLayers = in_sizes[3] / (128 * 128);    // 4
    const int nGraphs = out_size / 160;               // 64

    const int* srcArr = ei;
    const int* dstArr = ei + nEdges;

    // workspace layout
    int*   counts   = (int*)d_ws;                 // nNodes
    int*   offsets  = counts + nNodes;            // nNodes + 1
    int*   cursor   = offsets + nNodes + 1;       // nNodes
    int*   partials = cursor + nNodes;            // 256
    float* gsums    = (float*)(partials + 256);   // nGraphs * 128
    int*   ssrc     = (int*)(gsums + (size_t)nGraphs * 128);   // nEdges
    size_t zeroWords = (size_t)nNodes * 3 + 1 + 256 + (size_t)nGraphs * 128;

    const int wTotal = nLayers * 2 * 16384;       // frag-ordered split weights
    unsigned short* whf = (unsigned short*)(ssrc + nEdges);    // wTotal
    unsigned short* wlf = whf + (size_t)wTotal;                // wTotal

    size_t byteOff = (size_t)((char*)(wlf + wTotal) - (char*)d_ws);
    byteOff = (byteOff + 63) & ~(size_t)63;
    unsigned short* zhbuf = (unsigned short*)((char*)d_ws + byteOff);   // nNodes*128 bf16
    unsigned short* zlbuf = zhbuf + (size_t)nNodes * 128;               // nNodes*128 bf16
    float*          hbuf  = (float*)(zlbuf + (size_t)nNodes * 128);     // nNodes*128 fp32

    hipMemsetAsync(d_ws, 0, zeroWords * sizeof(int), stream);

    const int nb = (nNodes + 255) / 256;
    const int eb = (nEdges + 255) / 256;

    gin_hist<<<eb, 256, 0, stream>>>(dstArr, nEdges, counts);
    gin_scan1<<<nb, 256, 0, stream>>>(counts, offsets, partials, nNodes);
    gin_scan2<<<1, 256, 0, stream>>>(partials, nb);
    gin_scan3<<<nb, 256, 0, stream>>>(offsets, partials, cursor, nNodes, nEdges);
    gin_scatter<<<eb, 256, 0, stream>>>(srcArr, dstArr, nEdges, cursor, ssrc);
    gin_wsplit<<<64, 256, 0, stream>>>(w1, w2, whf, wlf, wTotal);

    const int mb = (nNodes + 63) / 64;
    const float* hin = x;
    for (int L = 0; L < nLayers; ++L) {
        gin_agg<<<(nNodes + 3) / 4, 256, 0, stream>>>(hin, offsets, ssrc,
                                                      (unsigned int*)zhbuf,
                                                      (unsigned int*)zlbuf, nNodes);
        gin_mlp<<<mb, 256, 0, stream>>>(zhbuf, zlbuf, whf, wlf, 2 * L,
                                        b1 + (size_t)L * 128, b2 + (size_t)L * 128,
                                        hbuf, nNodes, (L < nLayers - 1) ? 1 : 0);
        hin = hbuf;
    }
    const int pb = (nNodes + POOL_CHUNK - 1) / POOL_CHUNK;
    gin_pool1<<<pb, 256, 0, stream>>>(hin, batch, nNodes, gsums);
    gin_pool2<<<nGraphs, 128, 0, stream>>>(gsums, batch, nNodes, wlin, blin, out, nGraphs);
}

// Round 4
// 514.199 us; speedup vs baseline: 1.3584x; 1.0216x over previous
//
#include <hip/hip_runtime.h>

// ---------------------------------------------------------------------------
// GIN forward: 4x [agg(sum) -> Linear+ReLU -> Linear (+ReLU)] -> mean-pool -> head
// N_NODES=50000, N_EDGES=640000, D=128, N_GRAPHS=64, N_CLASSES=32
// R4: agg = 2 nodes/wave, interleaved unroll-4 (8 gathers in flight; was 4,
//     latency-bound at 3.0 TB/s read). z packed as one uint array (hi<<16|lo).
// ---------------------------------------------------------------------------

typedef short short8 __attribute__((ext_vector_type(8)));
typedef float floatx4 __attribute__((ext_vector_type(4)));

__device__ __forceinline__ unsigned short f2bf(float x) {
    unsigned int u = __float_as_uint(x);
    u += 0x7fffu + ((u >> 16) & 1u);          // RNE
    return (unsigned short)(u >> 16);
}
__device__ __forceinline__ float bf2f(unsigned short h) {
    return __uint_as_float(((unsigned int)h) << 16);
}
__device__ __forceinline__ unsigned int packsplit(float v) {
    unsigned short h = f2bf(v);
    unsigned short l = f2bf(v - bf2f(h));
    return ((unsigned)h << 16) | (unsigned)l;
}

// ---------------- CSR build ----------------

__global__ __launch_bounds__(256) void gin_hist(const int* __restrict__ dst,
                                                int nEdges,
                                                int* __restrict__ counts) {
    int i = blockIdx.x * 256 + threadIdx.x;
    if (i < nEdges) atomicAdd(&counts[dst[i]], 1);
}

__global__ __launch_bounds__(256) void gin_scan1(const int* __restrict__ counts,
                                                 int* __restrict__ offsets,
                                                 int* __restrict__ partials, int n) {
    __shared__ int s[256];
    int t = threadIdx.x;
    int i = blockIdx.x * 256 + t;
    int v = (i < n) ? counts[i] : 0;
    s[t] = v;
    __syncthreads();
    for (int off = 1; off < 256; off <<= 1) {
        int u = 0;
        if (t >= off) u = s[t - off];
        __syncthreads();
        s[t] += u;
        __syncthreads();
    }
    if (i < n) offsets[i] = s[t] - v;
    if (t == 255) partials[blockIdx.x] = s[255];
}

__global__ __launch_bounds__(256) void gin_scan2(int* partials, int nb) {
    __shared__ int s[256];
    int t = threadIdx.x;
    int v = (t < nb) ? partials[t] : 0;
    s[t] = v;
    __syncthreads();
    for (int off = 1; off < 256; off <<= 1) {
        int u = 0;
        if (t >= off) u = s[t - off];
        __syncthreads();
        s[t] += u;
        __syncthreads();
    }
    partials[t] = s[t] - v;
}

__global__ __launch_bounds__(256) void gin_scan3(int* __restrict__ offsets,
                                                 const int* __restrict__ partials,
                                                 int* __restrict__ cursor,
                                                 int n, int nEdges) {
    int i = blockIdx.x * 256 + threadIdx.x;
    if (i < n) {
        int o = offsets[i] + partials[blockIdx.x];
        offsets[i] = o;
        cursor[i]  = o;
    }
    if (i == 0) offsets[n] = nEdges;
}

__global__ __launch_bounds__(256) void gin_scatter(const int* __restrict__ src,
                                                   const int* __restrict__ dst,
                                                   int nEdges,
                                                   int* __restrict__ cursor,
                                                   int* __restrict__ ssrc) {
    int i = blockIdx.x * 256 + threadIdx.x;
    if (i < nEdges) {
        int p = atomicAdd(&cursor[dst[i]], 1);
        ssrc[p] = src[i];
    }
}

// ---------------- weight split into MFMA B-fragment order --------------------
// Wf[mat][kc(4)][ct(8)][lane(64)][j(8)], value = W[kc*32+(lane>>4)*8+j][ct*16+(lane&15)]

__global__ __launch_bounds__(256) void gin_wsplit(const float* __restrict__ w1,
                                                  const float* __restrict__ w2,
                                                  unsigned short* __restrict__ whf,
                                                  unsigned short* __restrict__ wlf,
                                                  int total) {
    for (int idx = blockIdx.x * 256 + threadIdx.x; idx < total; idx += gridDim.x * 256) {
        int mat  = idx >> 14;
        int rem  = idx & 16383;
        int kc   = rem >> 12;
        int ct   = (rem >> 9) & 7;
        int lane = (rem >> 3) & 63;
        int j    = rem & 7;
        int row = kc * 32 + (lane >> 4) * 8 + j;
        int col = ct * 16 + (lane & 15);
        int L = mat >> 1;
        const float* W = (mat & 1) ? (w2 + (size_t)L * 16384) : (w1 + (size_t)L * 16384);
        float x = W[row * 128 + col];
        unsigned short h = f2bf(x);
        unsigned short l = f2bf(x - bf2f(h));
        whf[idx] = h;
        wlf[idx] = l;
    }
}

// ---------------- aggregation: z[n] = h[n] + sum_{e} h[src_e], packed out ----
// 2 nodes per wave, interleaved unroll-4 => up to 8 gathers in flight.
// zp[row*128 + c] = (bf16_hi(z) << 16) | bf16_lo(z)

__global__ __launch_bounds__(256) void gin_agg(const float* __restrict__ hin,
                                               const int* __restrict__ offs,
                                               const int* __restrict__ ssrc,
                                               uint2* __restrict__ zp, int nNodes) {
    int wid  = (blockIdx.x * 256 + threadIdx.x) >> 6;
    int lane = threadIdx.x & 63;
    int nA = wid * 2, nB = wid * 2 + 1;
    if (nA >= nNodes) return;
    bool hasB = nB < nNodes;
    const float2* h2 = (const float2*)hin;

    float2 aA = h2[(size_t)nA * 64 + lane];                       // self terms
    float2 aB = hasB ? h2[(size_t)nB * 64 + lane] : make_float2(0.f, 0.f);
    int eA = offs[nA],               endA = offs[nA + 1];
    int eB = hasB ? offs[nB] : 0,    endB = hasB ? offs[nB + 1] : 0;

    // interleaved main loop: 8 gathers issued per iteration
    while (eA + 4 <= endA && eB + 4 <= endB) {
        int sA0 = ssrc[eA], sA1 = ssrc[eA + 1], sA2 = ssrc[eA + 2], sA3 = ssrc[eA + 3];
        int sB0 = ssrc[eB], sB1 = ssrc[eB + 1], sB2 = ssrc[eB + 2], sB3 = ssrc[eB + 3];
        float2 vA0 = h2[(size_t)sA0 * 64 + lane];
        float2 vA1 = h2[(size_t)sA1 * 64 + lane];
        float2 vA2 = h2[(size_t)sA2 * 64 + lane];
        float2 vA3 = h2[(size_t)sA3 * 64 + lane];
        float2 vB0 = h2[(size_t)sB0 * 64 + lane];
        float2 vB1 = h2[(size_t)sB1 * 64 + lane];
        float2 vB2 = h2[(size_t)sB2 * 64 + lane];
        float2 vB3 = h2[(size_t)sB3 * 64 + lane];
        aA.x += (vA0.x + vA1.x) + (vA2.x + vA3.x);
        aA.y += (vA0.y + vA1.y) + (vA2.y + vA3.y);
        aB.x += (vB0.x + vB1.x) + (vB2.x + vB3.x);
        aB.y += (vB0.y + vB1.y) + (vB2.y + vB3.y);
        eA += 4; eB += 4;
    }
    // A tail
    for (; eA + 4 <= endA; eA += 4) {
        int s0 = ssrc[eA], s1 = ssrc[eA + 1], s2 = ssrc[eA + 2], s3 = ssrc[eA + 3];
        float2 v0 = h2[(size_t)s0 * 64 + lane];
        float2 v1 = h2[(size_t)s1 * 64 + lane];
        float2 v2 = h2[(size_t)s2 * 64 + lane];
        float2 v3 = h2[(size_t)s3 * 64 + lane];
        aA.x += (v0.x + v1.x) + (v2.x + v3.x);
        aA.y += (v0.y + v1.y) + (v2.y + v3.y);
    }
    for (; eA < endA; ++eA) {
        float2 v = h2[(size_t)ssrc[eA] * 64 + lane];
        aA.x += v.x; aA.y += v.y;
    }
    // B tail
    for (; eB + 4 <= endB; eB += 4) {
        int s0 = ssrc[eB], s1 = ssrc[eB + 1], s2 = ssrc[eB + 2], s3 = ssrc[eB + 3];
        float2 v0 = h2[(size_t)s0 * 64 + lane];
        float2 v1 = h2[(size_t)s1 * 64 + lane];
        float2 v2 = h2[(size_t)s2 * 64 + lane];
        float2 v3 = h2[(size_t)s3 * 64 + lane];
        aB.x += (v0.x + v1.x) + (v2.x + v3.x);
        aB.y += (v0.y + v1.y) + (v2.y + v3.y);
    }
    for (; eB < endB; ++eB) {
        float2 v = h2[(size_t)ssrc[eB] * 64 + lane];
        aB.x += v.x; aB.y += v.y;
    }

    zp[(size_t)nA * 64 + lane] = make_uint2(packsplit(aA.x), packsplit(aA.y));
    if (hasB)
        zp[(size_t)nB * 64 + lane] = make_uint2(packsplit(aB.x), packsplit(aB.y));
}

// ---------------- fused MLP: h = [relu](relu(z@W1+b1)@W2+b2) ----------------
// Block = 64 rows x 128 cols, 4 waves; wave w owns coltiles 2w, 2w+1.
// 16x16x32 bf16 MFMA, 3-term split (hi@hi + lo@hi + hi@lo).
// z comes in packed (hi<<16|lo); y1 lives in LDS in the same packed form.

__global__ __launch_bounds__(256) void gin_mlp(const unsigned int* __restrict__ zp,
                                               const unsigned short* __restrict__ whf,
                                               const unsigned short* __restrict__ wlf,
                                               int matBase,
                                               const float* __restrict__ b1p,
                                               const float* __restrict__ b2p,
                                               float* __restrict__ hout,
                                               int nRows, int doRelu2) {
    __shared__ unsigned int y1s[64 * 132];
    const int tid = threadIdx.x;
    const int w = tid >> 6, lane = tid & 63;
    const int lo4 = lane & 15, hi4 = lane >> 4;
    const int rowbase = blockIdx.x * 64;

    short8 bh[2][4], bl[2][4];
#pragma unroll
    for (int ct = 0; ct < 2; ++ct)
#pragma unroll
        for (int kc = 0; kc < 4; ++kc) {
            size_t o = ((((size_t)matBase * 4 + kc) * 8 + (2 * w + ct)) * 64 + lane) * 8;
            bh[ct][kc] = *(const short8*)(whf + o);
            bl[ct][kc] = *(const short8*)(wlf + o);
        }

    floatx4 acc[4][2];
#pragma unroll
    for (int rg = 0; rg < 4; ++rg)
#pragma unroll
        for (int ct = 0; ct < 2; ++ct) acc[rg][ct] = (floatx4)0.f;

    // ---- phase 1: y1 = relu(z @ W1 + b1), A from packed global z
#pragma unroll
    for (int rg = 0; rg < 4; ++rg) {
        int row = rowbase + rg * 16 + lo4;
        bool ok = row < nRows;
        const unsigned int* pz = zp + (size_t)row * 128 + hi4 * 8;
#pragma unroll
        for (int kc = 0; kc < 4; ++kc) {
            short8 ah = {0,0,0,0,0,0,0,0}, al = {0,0,0,0,0,0,0,0};
            if (ok) {
                uint4 u0 = *(const uint4*)(pz + kc * 32);
                uint4 u1 = *(const uint4*)(pz + kc * 32 + 4);
                ah[0] = (short)(u0.x >> 16); al[0] = (short)u0.x;
                ah[1] = (short)(u0.y >> 16); al[1] = (short)u0.y;
                ah[2] = (short)(u0.z >> 16); al[2] = (short)u0.z;
                ah[3] = (short)(u0.w >> 16); al[3] = (short)u0.w;
                ah[4] = (short)(u1.x >> 16); al[4] = (short)u1.x;
                ah[5] = (short)(u1.y >> 16); al[5] = (short)u1.y;
                ah[6] = (short)(u1.z >> 16); al[6] = (short)u1.z;
                ah[7] = (short)(u1.w >> 16); al[7] = (short)u1.w;
            }
#pragma unroll
            for (int ct = 0; ct < 2; ++ct) {
                acc[rg][ct] = __builtin_amdgcn_mfma_f32_16x16x32_bf16(ah, bh[ct][kc], acc[rg][ct], 0, 0, 0);
                acc[rg][ct] = __builtin_amdgcn_mfma_f32_16x16x32_bf16(al, bh[ct][kc], acc[rg][ct], 0, 0, 0);
                acc[rg][ct] = __builtin_amdgcn_mfma_f32_16x16x32_bf16(ah, bl[ct][kc], acc[rg][ct], 0, 0, 0);
            }
        }
    }

    // epilogue 1: bias + relu + split -> LDS (packed hi|lo)
    float bb1_0 = b1p[w * 32 + lo4];
    float bb1_1 = b1p[w * 32 + 16 + lo4];
#pragma unroll
    for (int rg = 0; rg < 4; ++rg)
#pragma unroll
        for (int ct = 0; ct < 2; ++ct) {
            float bb = ct ? bb1_1 : bb1_0;
#pragma unroll
            for (int r = 0; r < 4; ++r) {
                float v = fmaxf(acc[rg][ct][r] + bb, 0.f);
                int rl = rg * 16 + hi4 * 4 + r;
                int cl = w * 32 + ct * 16 + lo4;
                y1s[rl * 132 + cl] = packsplit(v);
            }
        }
    __syncthreads();

    // ---- phase 2: h = y1 @ W2 + b2
#pragma unroll
    for (int ct = 0; ct < 2; ++ct)
#pragma unroll
        for (int kc = 0; kc < 4; ++kc) {
            size_t o = ((((size_t)(matBase + 1) * 4 + kc) * 8 + (2 * w + ct)) * 64 + lane) * 8;
            bh[ct][kc] = *(const short8*)(whf + o);
            bl[ct][kc] = *(const short8*)(wlf + o);
        }
#pragma unroll
    for (int rg = 0; rg < 4; ++rg)
#pragma unroll
        for (int ct = 0; ct < 2; ++ct) acc[rg][ct] = (floatx4)0.f;

#pragma unroll
    for (int rg = 0; rg < 4; ++rg) {
#pragma unroll
        for (int kc = 0; kc < 4; ++kc) {
            const unsigned int* p = &y1s[(rg * 16 + lo4) * 132 + kc * 32 + hi4 * 8];
            uint4 u0 = *(const uint4*)p;
            uint4 u1 = *(const uint4*)(p + 4);
            short8 ah, al;
            ah[0] = (short)(u0.x >> 16); al[0] = (short)u0.x;
            ah[1] = (short)(u0.y >> 16); al[1] = (short)u0.y;
            ah[2] = (short)(u0.z >> 16); al[2] = (short)u0.z;
            ah[3] = (short)(u0.w >> 16); al[3] = (short)u0.w;
            ah[4] = (short)(u1.x >> 16); al[4] = (short)u1.x;
            ah[5] = (short)(u1.y >> 16); al[5] = (short)u1.y;
            ah[6] = (short)(u1.z >> 16); al[6] = (short)u1.z;
            ah[7] = (short)(u1.w >> 16); al[7] = (short)u1.w;
#pragma unroll
            for (int ct = 0; ct < 2; ++ct) {
                acc[rg][ct] = __builtin_amdgcn_mfma_f32_16x16x32_bf16(ah, bh[ct][kc], acc[rg][ct], 0, 0, 0);
                acc[rg][ct] = __builtin_amdgcn_mfma_f32_16x16x32_bf16(al, bh[ct][kc], acc[rg][ct], 0, 0, 0);
                acc[rg][ct] = __builtin_amdgcn_mfma_f32_16x16x32_bf16(ah, bl[ct][kc], acc[rg][ct], 0, 0, 0);
            }
        }
    }

    float bb2_0 = b2p[w * 32 + lo4];
    float bb2_1 = b2p[w * 32 + 16 + lo4];
#pragma unroll
    for (int rg = 0; rg < 4; ++rg)
#pragma unroll
        for (int ct = 0; ct < 2; ++ct) {
            float bb = ct ? bb2_1 : bb2_0;
#pragma unroll
            for (int r = 0; r < 4; ++r) {
                int row = rowbase + rg * 16 + hi4 * 4 + r;
                if (row < nRows) {
                    float v = acc[rg][ct][r] + bb;
                    if (doRelu2) v = fmaxf(v, 0.f);
                    hout[(size_t)row * 128 + w * 32 + ct * 16 + lo4] = v;
                }
            }
        }
}

// ---------------- mean pool, phase 1: chunked partial sums -------------------

#define POOL_CHUNK 256

__global__ __launch_bounds__(256) void gin_pool1(const float* __restrict__ h,
                                                 const int* __restrict__ batch, int nNodes,
                                                 float* __restrict__ gsums) {
    int t = threadIdx.x;
    int c = t & 127, half = t >> 7;
    int start = blockIdx.x * POOL_CHUNK;
    int end = start + POOL_CHUNK;
    if (end > nNodes) end = nNodes;
    int n = start + half;
    if (n >= end) return;
    int gcur = batch[n];
    float acc = 0.f;
    for (; n < end; n += 2) {
        int g = batch[n];
        if (g != gcur) {
            atomicAdd(&gsums[gcur * 128 + c], acc);
            acc = 0.f;
            gcur = g;
        }
        acc += h[(size_t)n * 128 + c];
    }
    atomicAdd(&gsums[gcur * 128 + c], acc);
}

// ---------------- mean pool, phase 2: divide by count + classifier head ------

__device__ __forceinline__ int lb_search(const int* __restrict__ a, int n, int key) {
    int lo = 0, hi = n;
    while (lo < hi) {
        int m = (lo + hi) >> 1;
        if (a[m] < key) lo = m + 1; else hi = m;
    }
    return lo;
}

__global__ __launch_bounds__(128) void gin_pool2(const float* __restrict__ gsums,
                                                 const int* __restrict__ batch, int nNodes,
                                                 const float* __restrict__ wlin,
                                                 const float* __restrict__ blin,
                                                 float* __restrict__ out, int nGraphs) {
    __shared__ float sp[128];
    int g = blockIdx.x;
    int t = threadIdx.x;
    int start = lb_search(batch, nNodes, g);
    int end   = lb_search(batch, nNodes, g + 1);
    float cnt = (float)(end - start);
    float p = gsums[(size_t)g * 128 + t] / fmaxf(cnt, 1.0f);
    out[(size_t)g * 128 + t] = p;
    sp[t] = p;
    __syncthreads();
    if (t < 32) {
        float s = blin[t];
        for (int k = 0; k < 128; ++k) s += sp[k] * wlin[k * 32 + t];
        out[(size_t)nGraphs * 128 + g * 32 + t] = s;
    }
}

// ---------------------------------------------------------------------------

extern "C" void kernel_launch(void* const* d_in, const int* in_sizes, int n_in,
                              void* d_out, int out_size, void* d_ws, size_t ws_size,
                              hipStream_t stream) {
    const float* x     = (const float*)d_in[0];
    const int*   ei    = (const int*)d_in[1];
    const int*   batch = (const int*)d_in[2];
    const float* w1    = (const float*)d_in[3];
    const float* b1    = (const float*)d_in[4];
    const float* w2    = (const float*)d_in[5];
    const float* b2    = (const float*)d_in[6];
    const float* wlin  = (const float*)d_in[7];
    const float* blin  = (const float*)d_in[8];
    float* out = (float*)d_out;

    const int nNodes  = in_sizes[0] / 128;            // 50000
    const int nEdges  = in_sizes[1] / 2;              // 640000
    const int nLayers = in_sizes[3] / (128 * 128);    // 4
    const int nGraphs = out_size / 160;               // 64

    const int* srcArr = ei;
    const int* dstArr = ei + nEdges;

    // workspace layout
    int*   counts   = (int*)d_ws;                 // nNodes
    int*   offsets  = counts + nNodes;            // nNodes + 1
    int*   cursor   = offsets + nNodes + 1;       // nNodes
    int*   partials = cursor + nNodes;            // 256
    float* gsums    = (float*)(partials + 256);   // nGraphs * 128
    int*   ssrc     = (int*)(gsums + (size_t)nGraphs * 128);   // nEdges
    size_t zeroWords = (size_t)nNodes * 3 + 1 + 256 + (size_t)nGraphs * 128;

    const int wTotal = nLayers * 2 * 16384;       // frag-ordered split weights
    unsigned short* whf = (unsigned short*)(ssrc + nEdges);    // wTotal
    unsigned short* wlf = whf + (size_t)wTotal;                // wTotal

    size_t byteOff = (size_t)((char*)(wlf + wTotal) - (char*)d_ws);
    byteOff = (byteOff + 63) & ~(size_t)63;
    unsigned int* zpbuf = (unsigned int*)((char*)d_ws + byteOff);       // nNodes*128 uint
    float*        hbuf  = (float*)(zpbuf + (size_t)nNodes * 128);       // nNodes*128 fp32

    hipMemsetAsync(d_ws, 0, zeroWords * sizeof(int), stream);

    const int nb = (nNodes + 255) / 256;
    const int eb = (nEdges + 255) / 256;

    gin_hist<<<eb, 256, 0, stream>>>(dstArr, nEdges, counts);
    gin_scan1<<<nb, 256, 0, stream>>>(counts, offsets, partials, nNodes);
    gin_scan2<<<1, 256, 0, stream>>>(partials, nb);
    gin_scan3<<<nb, 256, 0, stream>>>(offsets, partials, cursor, nNodes, nEdges);
    gin_scatter<<<eb, 256, 0, stream>>>(srcArr, dstArr, nEdges, cursor, ssrc);
    gin_wsplit<<<64, 256, 0, stream>>>(w1, w2, whf, wlf, wTotal);

    const int mb = (nNodes + 63) / 64;
    const int ab = (nNodes + 7) / 8;              // 2 nodes/wave, 4 waves/block
    const float* hin = x;
    for (int L = 0; L < nLayers; ++L) {
        gin_agg<<<ab, 256, 0, stream>>>(hin, offsets, ssrc, (uint2*)zpbuf, nNodes);
        gin_mlp<<<mb, 256, 0, stream>>>(zpbuf, whf, wlf, 2 * L,
                                        b1 + (size_t)L * 128, b2 + (size_t)L * 128,
                                        hbuf, nNodes, (L < nLayers - 1) ? 1 : 0);
        hin = hbuf;
    }
    const int pb = (nNodes + POOL_CHUNK - 1) / POOL_CHUNK;
    gin_pool1<<<pb, 256, 0, stream>>>(hin, batch, nNodes, gsums);
    gin_pool2<<<nGraphs, 128, 0, stream>>>(gsums, batch, nNodes, wlin, blin, out, nGraphs);
}

// Round 5
// 494.847 us; speedup vs baseline: 1.4116x; 1.0391x over previous
//
#include <hip/hip_runtime.h>

// ---------------------------------------------------------------------------
// GIN forward: 4x [agg(sum) -> Linear+ReLU -> Linear (+ReLU)] -> mean-pool -> head
// N_NODES=50000, N_EDGES=640000, D=128, N_GRAPHS=64, N_CLASSES=32
// R5: fully fused per-layer kernel (32-row tile): gather->z in LDS (no HBM
//     round-trip) -> MFMA MLP (split-bf16, 3-term) -> store h, or pool into
//     gsums on the last layer (h never hits HBM). Ping-pong h buffers.
// ---------------------------------------------------------------------------

typedef short short8 __attribute__((ext_vector_type(8)));
typedef float floatx4 __attribute__((ext_vector_type(4)));

__device__ __forceinline__ unsigned short f2bf(float x) {
    unsigned int u = __float_as_uint(x);
    u += 0x7fffu + ((u >> 16) & 1u);          // RNE
    return (unsigned short)(u >> 16);
}
__device__ __forceinline__ float bf2f(unsigned short h) {
    return __uint_as_float(((unsigned int)h) << 16);
}
__device__ __forceinline__ unsigned int packsplit(float v) {
    unsigned short h = f2bf(v);
    unsigned short l = f2bf(v - bf2f(h));
    return ((unsigned)h << 16) | (unsigned)l;
}

// ---------------- CSR build ----------------

__global__ __launch_bounds__(256) void gin_hist(const int* __restrict__ dst,
                                                int nEdges,
                                                int* __restrict__ counts) {
    int i = blockIdx.x * 256 + threadIdx.x;
    if (i < nEdges) atomicAdd(&counts[dst[i]], 1);
}

__global__ __launch_bounds__(256) void gin_scan1(const int* __restrict__ counts,
                                                 int* __restrict__ offsets,
                                                 int* __restrict__ partials, int n) {
    __shared__ int s[256];
    int t = threadIdx.x;
    int i = blockIdx.x * 256 + t;
    int v = (i < n) ? counts[i] : 0;
    s[t] = v;
    __syncthreads();
    for (int off = 1; off < 256; off <<= 1) {
        int u = 0;
        if (t >= off) u = s[t - off];
        __syncthreads();
        s[t] += u;
        __syncthreads();
    }
    if (i < n) offsets[i] = s[t] - v;
    if (t == 255) partials[blockIdx.x] = s[255];
}

__global__ __launch_bounds__(256) void gin_scan2(int* partials, int nb) {
    __shared__ int s[256];
    int t = threadIdx.x;
    int v = (t < nb) ? partials[t] : 0;
    s[t] = v;
    __syncthreads();
    for (int off = 1; off < 256; off <<= 1) {
        int u = 0;
        if (t >= off) u = s[t - off];
        __syncthreads();
        s[t] += u;
        __syncthreads();
    }
    partials[t] = s[t] - v;
}

__global__ __launch_bounds__(256) void gin_scan3(int* __restrict__ offsets,
                                                 const int* __restrict__ partials,
                                                 int* __restrict__ cursor,
                                                 int n, int nEdges) {
    int i = blockIdx.x * 256 + threadIdx.x;
    if (i < n) {
        int o = offsets[i] + partials[blockIdx.x];
        offsets[i] = o;
        cursor[i]  = o;
    }
    if (i == 0) offsets[n] = nEdges;
}

__global__ __launch_bounds__(256) void gin_scatter(const int* __restrict__ src,
                                                   const int* __restrict__ dst,
                                                   int nEdges,
                                                   int* __restrict__ cursor,
                                                   int* __restrict__ ssrc) {
    int i = blockIdx.x * 256 + threadIdx.x;
    if (i < nEdges) {
        int p = atomicAdd(&cursor[dst[i]], 1);
        ssrc[p] = src[i];
    }
}

// ---------------- weight split into MFMA B-fragment order --------------------
// Wf[mat][kc(4)][ct(8)][lane(64)][j(8)], value = W[kc*32+(lane>>4)*8+j][ct*16+(lane&15)]

__global__ __launch_bounds__(256) void gin_wsplit(const float* __restrict__ w1,
                                                  const float* __restrict__ w2,
                                                  unsigned short* __restrict__ whf,
                                                  unsigned short* __restrict__ wlf,
                                                  int total) {
    for (int idx = blockIdx.x * 256 + threadIdx.x; idx < total; idx += gridDim.x * 256) {
        int mat  = idx >> 14;
        int rem  = idx & 16383;
        int kc   = rem >> 12;
        int ct   = (rem >> 9) & 7;
        int lane = (rem >> 3) & 63;
        int j    = rem & 7;
        int row = kc * 32 + (lane >> 4) * 8 + j;
        int col = ct * 16 + (lane & 15);
        int L = mat >> 1;
        const float* W = (mat & 1) ? (w2 + (size_t)L * 16384) : (w1 + (size_t)L * 16384);
        float x = W[row * 128 + col];
        unsigned short h = f2bf(x);
        unsigned short l = f2bf(x - bf2f(h));
        whf[idx] = h;
        wlf[idx] = l;
    }
}

// ---------------- fused layer: agg(LDS) -> MLP(MFMA) -> store h / pool -------
// 32-row tile, 4 waves. Wave w: gathers rows w*8..w*8+7 (2-node interleave,
// 8 gathers in flight), then owns coltiles 2w,2w+1 across both rowgroups.
// z and y1 live in LDS packed (hi<<16|lo), row stride 132 (bank-safe).

#define TM 32

__global__ __launch_bounds__(256) void gin_layer(const float* __restrict__ hin,
                                                 const int* __restrict__ offs,
                                                 const int* __restrict__ ssrc,
                                                 const unsigned short* __restrict__ whf,
                                                 const unsigned short* __restrict__ wlf,
                                                 int matBase,
                                                 const float* __restrict__ b1p,
                                                 const float* __restrict__ b2p,
                                                 float* __restrict__ hout,
                                                 const int* __restrict__ batch,
                                                 float* __restrict__ gsums,
                                                 int nRows, int lastLayer) {
    __shared__ unsigned int zs[TM * 132];
    __shared__ unsigned int y1s[TM * 132];
    const int tid = threadIdx.x;
    const int w = tid >> 6, lane = tid & 63;
    const int lo4 = lane & 15, hi4 = lane >> 4;
    const int rowbase = blockIdx.x * TM;

    // ---- phase 1 weights (issue early; independent of gather)
    short8 bh[2][4], bl[2][4];
#pragma unroll
    for (int ct = 0; ct < 2; ++ct)
#pragma unroll
        for (int kc = 0; kc < 4; ++kc) {
            size_t o = ((((size_t)matBase * 4 + kc) * 8 + (2 * w + ct)) * 64 + lane) * 8;
            bh[ct][kc] = *(const short8*)(whf + o);
            bl[ct][kc] = *(const short8*)(wlf + o);
        }

    // ---- gather phase: z rows w*8 .. w*8+7, 2 nodes interleaved
    const float2* h2 = (const float2*)hin;
    const int base = rowbase + w * 8;
#pragma unroll
    for (int pp = 0; pp < 4; ++pp) {
        int nA = base + 2 * pp, nB = nA + 1;
        bool okA = nA < nRows, okB = nB < nRows;
        float2 aA = make_float2(0.f, 0.f), aB = make_float2(0.f, 0.f);
        if (okA) aA = h2[(size_t)nA * 64 + lane];
        if (okB) aB = h2[(size_t)nB * 64 + lane];
        int eA = okA ? offs[nA] : 0, endA = okA ? offs[nA + 1] : 0;
        int eB = okB ? offs[nB] : 0, endB = okB ? offs[nB + 1] : 0;

        while (eA + 4 <= endA && eB + 4 <= endB) {
            int sA0 = ssrc[eA], sA1 = ssrc[eA + 1], sA2 = ssrc[eA + 2], sA3 = ssrc[eA + 3];
            int sB0 = ssrc[eB], sB1 = ssrc[eB + 1], sB2 = ssrc[eB + 2], sB3 = ssrc[eB + 3];
            float2 vA0 = h2[(size_t)sA0 * 64 + lane];
            float2 vA1 = h2[(size_t)sA1 * 64 + lane];
            float2 vA2 = h2[(size_t)sA2 * 64 + lane];
            float2 vA3 = h2[(size_t)sA3 * 64 + lane];
            float2 vB0 = h2[(size_t)sB0 * 64 + lane];
            float2 vB1 = h2[(size_t)sB1 * 64 + lane];
            float2 vB2 = h2[(size_t)sB2 * 64 + lane];
            float2 vB3 = h2[(size_t)sB3 * 64 + lane];
            aA.x += (vA0.x + vA1.x) + (vA2.x + vA3.x);
            aA.y += (vA0.y + vA1.y) + (vA2.y + vA3.y);
            aB.x += (vB0.x + vB1.x) + (vB2.x + vB3.x);
            aB.y += (vB0.y + vB1.y) + (vB2.y + vB3.y);
            eA += 4; eB += 4;
        }
        for (; eA + 4 <= endA; eA += 4) {
            int s0 = ssrc[eA], s1 = ssrc[eA + 1], s2 = ssrc[eA + 2], s3 = ssrc[eA + 3];
            float2 v0 = h2[(size_t)s0 * 64 + lane];
            float2 v1 = h2[(size_t)s1 * 64 + lane];
            float2 v2 = h2[(size_t)s2 * 64 + lane];
            float2 v3 = h2[(size_t)s3 * 64 + lane];
            aA.x += (v0.x + v1.x) + (v2.x + v3.x);
            aA.y += (v0.y + v1.y) + (v2.y + v3.y);
        }
        for (; eA < endA; ++eA) {
            float2 v = h2[(size_t)ssrc[eA] * 64 + lane];
            aA.x += v.x; aA.y += v.y;
        }
        for (; eB + 4 <= endB; eB += 4) {
            int s0 = ssrc[eB], s1 = ssrc[eB + 1], s2 = ssrc[eB + 2], s3 = ssrc[eB + 3];
            float2 v0 = h2[(size_t)s0 * 64 + lane];
            float2 v1 = h2[(size_t)s1 * 64 + lane];
            float2 v2 = h2[(size_t)s2 * 64 + lane];
            float2 v3 = h2[(size_t)s3 * 64 + lane];
            aB.x += (v0.x + v1.x) + (v2.x + v3.x);
            aB.y += (v0.y + v1.y) + (v2.y + v3.y);
        }
        for (; eB < endB; ++eB) {
            float2 v = h2[(size_t)ssrc[eB] * 64 + lane];
            aB.x += v.x; aB.y += v.y;
        }
        int rA = nA - rowbase, rB = rA + 1;
        zs[rA * 132 + 2 * lane]     = packsplit(aA.x);
        zs[rA * 132 + 2 * lane + 1] = packsplit(aA.y);
        zs[rB * 132 + 2 * lane]     = packsplit(aB.x);
        zs[rB * 132 + 2 * lane + 1] = packsplit(aB.y);
    }
    __syncthreads();

    // ---- MLP phase 1: y1 = relu(z @ W1 + b1)
    floatx4 acc[2][2];
#pragma unroll
    for (int rg = 0; rg < 2; ++rg)
#pragma unroll
        for (int ct = 0; ct < 2; ++ct) acc[rg][ct] = (floatx4)0.f;

#pragma unroll
    for (int rg = 0; rg < 2; ++rg) {
#pragma unroll
        for (int kc = 0; kc < 4; ++kc) {
            const unsigned int* p = &zs[(rg * 16 + lo4) * 132 + kc * 32 + hi4 * 8];
            uint4 u0 = *(const uint4*)p;
            uint4 u1 = *(const uint4*)(p + 4);
            short8 ah, al;
            ah[0] = (short)(u0.x >> 16); al[0] = (short)u0.x;
            ah[1] = (short)(u0.y >> 16); al[1] = (short)u0.y;
            ah[2] = (short)(u0.z >> 16); al[2] = (short)u0.z;
            ah[3] = (short)(u0.w >> 16); al[3] = (short)u0.w;
            ah[4] = (short)(u1.x >> 16); al[4] = (short)u1.x;
            ah[5] = (short)(u1.y >> 16); al[5] = (short)u1.y;
            ah[6] = (short)(u1.z >> 16); al[6] = (short)u1.z;
            ah[7] = (short)(u1.w >> 16); al[7] = (short)u1.w;
#pragma unroll
            for (int ct = 0; ct < 2; ++ct) {
                acc[rg][ct] = __builtin_amdgcn_mfma_f32_16x16x32_bf16(ah, bh[ct][kc], acc[rg][ct], 0, 0, 0);
                acc[rg][ct] = __builtin_amdgcn_mfma_f32_16x16x32_bf16(al, bh[ct][kc], acc[rg][ct], 0, 0, 0);
                acc[rg][ct] = __builtin_amdgcn_mfma_f32_16x16x32_bf16(ah, bl[ct][kc], acc[rg][ct], 0, 0, 0);
            }
        }
    }

    float bb1_0 = b1p[w * 32 + lo4];
    float bb1_1 = b1p[w * 32 + 16 + lo4];
#pragma unroll
    for (int rg = 0; rg < 2; ++rg)
#pragma unroll
        for (int ct = 0; ct < 2; ++ct) {
            float bb = ct ? bb1_1 : bb1_0;
#pragma unroll
            for (int r = 0; r < 4; ++r) {
                float v = fmaxf(acc[rg][ct][r] + bb, 0.f);
                int rl = rg * 16 + hi4 * 4 + r;
                int cl = w * 32 + ct * 16 + lo4;
                y1s[rl * 132 + cl] = packsplit(v);
            }
        }
    __syncthreads();

    // ---- MLP phase 2: h = y1 @ W2 + b2
#pragma unroll
    for (int ct = 0; ct < 2; ++ct)
#pragma unroll
        for (int kc = 0; kc < 4; ++kc) {
            size_t o = ((((size_t)(matBase + 1) * 4 + kc) * 8 + (2 * w + ct)) * 64 + lane) * 8;
            bh[ct][kc] = *(const short8*)(whf + o);
            bl[ct][kc] = *(const short8*)(wlf + o);
        }
#pragma unroll
    for (int rg = 0; rg < 2; ++rg)
#pragma unroll
        for (int ct = 0; ct < 2; ++ct) acc[rg][ct] = (floatx4)0.f;

#pragma unroll
    for (int rg = 0; rg < 2; ++rg) {
#pragma unroll
        for (int kc = 0; kc < 4; ++kc) {
            const unsigned int* p = &y1s[(rg * 16 + lo4) * 132 + kc * 32 + hi4 * 8];
            uint4 u0 = *(const uint4*)p;
            uint4 u1 = *(const uint4*)(p + 4);
            short8 ah, al;
            ah[0] = (short)(u0.x >> 16); al[0] = (short)u0.x;
            ah[1] = (short)(u0.y >> 16); al[1] = (short)u0.y;
            ah[2] = (short)(u0.z >> 16); al[2] = (short)u0.z;
            ah[3] = (short)(u0.w >> 16); al[3] = (short)u0.w;
            ah[4] = (short)(u1.x >> 16); al[4] = (short)u1.x;
            ah[5] = (short)(u1.y >> 16); al[5] = (short)u1.y;
            ah[6] = (short)(u1.z >> 16); al[6] = (short)u1.z;
            ah[7] = (short)(u1.w >> 16); al[7] = (short)u1.w;
#pragma unroll
            for (int ct = 0; ct < 2; ++ct) {
                acc[rg][ct] = __builtin_amdgcn_mfma_f32_16x16x32_bf16(ah, bh[ct][kc], acc[rg][ct], 0, 0, 0);
                acc[rg][ct] = __builtin_amdgcn_mfma_f32_16x16x32_bf16(al, bh[ct][kc], acc[rg][ct], 0, 0, 0);
                acc[rg][ct] = __builtin_amdgcn_mfma_f32_16x16x32_bf16(ah, bl[ct][kc], acc[rg][ct], 0, 0, 0);
            }
        }
    }

    float bb2_0 = b2p[w * 32 + lo4];
    float bb2_1 = b2p[w * 32 + 16 + lo4];

    if (!lastLayer) {
        // store h with inter-layer relu
#pragma unroll
        for (int rg = 0; rg < 2; ++rg)
#pragma unroll
            for (int ct = 0; ct < 2; ++ct) {
                float bb = ct ? bb2_1 : bb2_0;
#pragma unroll
                for (int r = 0; r < 4; ++r) {
                    int row = rowbase + rg * 16 + hi4 * 4 + r;
                    if (row < nRows) {
                        float v = fmaxf(acc[rg][ct][r] + bb, 0.f);
                        hout[(size_t)row * 128 + w * 32 + ct * 16 + lo4] = v;
                    }
                }
            }
    } else {
        // last layer: no relu, pool directly into gsums (h never hits HBM).
        // stash fp32 h into zs (all zs reads finished before the y1s barrier)
        float* zf = (float*)zs;
#pragma unroll
        for (int rg = 0; rg < 2; ++rg)
#pragma unroll
            for (int ct = 0; ct < 2; ++ct) {
                float bb = ct ? bb2_1 : bb2_0;
#pragma unroll
                for (int r = 0; r < 4; ++r) {
                    int rl = rg * 16 + hi4 * 4 + r;
                    int cl = w * 32 + ct * 16 + lo4;
                    zf[rl * 132 + cl] = acc[rg][ct][r] + bb;
                }
            }
        __syncthreads();
        int c = tid & 127, half = tid >> 7;
        int rmax = nRows - rowbase;
        if (rmax > TM) rmax = TM;
        float accp = 0.f;
        int gcur = -1;
        for (int r = half; r < rmax; r += 2) {
            int g = batch[rowbase + r];
            if (g != gcur) {
                if (gcur >= 0) atomicAdd(&gsums[gcur * 128 + c], accp);
                accp = 0.f;
                gcur = g;
            }
            accp += zf[r * 132 + c];
        }
        if (gcur >= 0) atomicAdd(&gsums[gcur * 128 + c], accp);
    }
}

// ---------------- finalize: divide by count + classifier head ----------------

__device__ __forceinline__ int lb_search(const int* __restrict__ a, int n, int key) {
    int lo = 0, hi = n;
    while (lo < hi) {
        int m = (lo + hi) >> 1;
        if (a[m] < key) lo = m + 1; else hi = m;
    }
    return lo;
}

__global__ __launch_bounds__(128) void gin_pool2(const float* __restrict__ gsums,
                                                 const int* __restrict__ batch, int nNodes,
                                                 const float* __restrict__ wlin,
                                                 const float* __restrict__ blin,
                                                 float* __restrict__ out, int nGraphs) {
    __shared__ float sp[128];
    int g = blockIdx.x;
    int t = threadIdx.x;
    int start = lb_search(batch, nNodes, g);
    int end   = lb_search(batch, nNodes, g + 1);
    float cnt = (float)(end - start);
    float p = gsums[(size_t)g * 128 + t] / fmaxf(cnt, 1.0f);
    out[(size_t)g * 128 + t] = p;
    sp[t] = p;
    __syncthreads();
    if (t < 32) {
        float s = blin[t];
        for (int k = 0; k < 128; ++k) s += sp[k] * wlin[k * 32 + t];
        out[(size_t)nGraphs * 128 + g * 32 + t] = s;
    }
}

// ---------------------------------------------------------------------------

extern "C" void kernel_launch(void* const* d_in, const int* in_sizes, int n_in,
                              void* d_out, int out_size, void* d_ws, size_t ws_size,
                              hipStream_t stream) {
    const float* x     = (const float*)d_in[0];
    const int*   ei    = (const int*)d_in[1];
    const int*   batch = (const int*)d_in[2];
    const float* w1    = (const float*)d_in[3];
    const float* b1    = (const float*)d_in[4];
    const float* w2    = (const float*)d_in[5];
    const float* b2    = (const float*)d_in[6];
    const float* wlin  = (const float*)d_in[7];
    const float* blin  = (const float*)d_in[8];
    float* out = (float*)d_out;

    const int nNodes  = in_sizes[0] / 128;            // 50000
    const int nEdges  = in_sizes[1] / 2;              // 640000
    const int nLayers = in_sizes[3] / (128 * 128);    // 4
    const int nGraphs = out_size / 160;               // 64

    const int* srcArr = ei;
    const int* dstArr = ei + nEdges;

    // workspace layout
    int*   counts   = (int*)d_ws;                 // nNodes
    int*   offsets  = counts + nNodes;            // nNodes + 1
    int*   cursor   = offsets + nNodes + 1;       // nNodes
    int*   partials = cursor + nNodes;            // 256
    float* gsums    = (float*)(partials + 256);   // nGraphs * 128
    int*   ssrc     = (int*)(gsums + (size_t)nGraphs * 128);   // nEdges
    size_t zeroWords = (size_t)nNodes * 3 + 1 + 256 + (size_t)nGraphs * 128;

    const int wTotal = nLayers * 2 * 16384;       // frag-ordered split weights
    unsigned short* whf = (unsigned short*)(ssrc + nEdges);    // wTotal
    unsigned short* wlf = whf + (size_t)wTotal;                // wTotal

    size_t byteOff = (size_t)((char*)(wlf + wTotal) - (char*)d_ws);
    byteOff = (byteOff + 63) & ~(size_t)63;
    float* bufA = (float*)((char*)d_ws + byteOff);             // nNodes*128 fp32
    float* bufB = bufA + (size_t)nNodes * 128;                 // nNodes*128 fp32

    hipMemsetAsync(d_ws, 0, zeroWords * sizeof(int), stream);

    const int nb = (nNodes + 255) / 256;
    const int eb = (nEdges + 255) / 256;

    gin_hist<<<eb, 256, 0, stream>>>(dstArr, nEdges, counts);
    gin_scan1<<<nb, 256, 0, stream>>>(counts, offsets, partials, nNodes);
    gin_scan2<<<1, 256, 0, stream>>>(partials, nb);
    gin_scan3<<<nb, 256, 0, stream>>>(offsets, partials, cursor, nNodes, nEdges);
    gin_scatter<<<eb, 256, 0, stream>>>(srcArr, dstArr, nEdges, cursor, ssrc);
    gin_wsplit<<<64, 256, 0, stream>>>(w1, w2, whf, wlf, wTotal);

    const int lb = (nNodes + TM - 1) / TM;
    const float* hin = x;
    float* bufs[2] = {bufA, bufB};
    for (int L = 0; L < nLayers; ++L) {
        int last = (L == nLayers - 1);
        float* hout = bufs[L & 1];
        gin_layer<<<lb, 256, 0, stream>>>(hin, offsets, ssrc, whf, wlf, 2 * L,
                                          b1 + (size_t)L * 128, b2 + (size_t)L * 128,
                                          hout, batch, gsums, nNodes, last);
        hin = hout;
    }
    gin_pool2<<<nGraphs, 128, 0, stream>>>(gsums, batch, nNodes, wlin, blin, out, nGraphs);
}